// Round 11
// baseline (245.563 us; speedup 1.0000x reference)
//
#include <hip/hip_runtime.h>
#include <hip/hip_bf16.h>

// Problem constants
#define BB 4
#define CC 768
#define CT 192
#define TT 2048
#define SS 1024
#define KK 12

typedef __attribute__((ext_vector_type(8))) short bfrag8;  // 8 bf16 = 4 VGPR
typedef __attribute__((ext_vector_type(4))) float f32x4;

// ---------------------------------------------------------------------------
// Fragment-layout convention (16x16x32 bf16 MFMA):
//   A: row m = lane&15, k-slot = 32*cc + (lane>>4)*8 + j
//   B: col n = lane&15, k-slot = 32*cc + (lane>>4)*8 + j
//   D: col n = lane&15, row m = (lane>>4)*4 + reg   (HW-verified)
// A/B use the SAME slot->k map so the contraction is exact.
//
// HARD CONSTRAINTS (measured R7-R10):
//  - toolchain pins arch-VGPR budget at 128 for these kernels; designs
//    must keep live sets ~<=124.
//  - occupancy is capped at 2 waves/SIMD by unified VGPR+AGPR usage
//    (~22% at ANY LDS size) -> latency must be hidden IN-wave (R11: bf
//    software pipeline).
// ---------------------------------------------------------------------------

__device__ inline unsigned pk2(float a, float b) {
    __hip_bfloat162 h2;
    h2.x = __float2bfloat16(a);
    h2.y = __float2bfloat16(b);
    return *reinterpret_cast<unsigned*>(&h2);
}
__device__ inline float unpk_lo(unsigned u) { return __uint_as_float(u << 16); }
__device__ inline float unpk_hi(unsigned u) {
    return __uint_as_float(u & 0xffff0000u);
}

// ---------------------------------------------------------------------------
// ONE pack kernel, 256 blocks (R10, proven):
//   blk 0..31   : textS/textC  (b = blk>>3, part = blk&7)
//   blk 32..127 : WP           (k = (blk-32)>>3, part = (blk-32)&7)
//   blk 128..255: yP via LDS transpose (b = idx>>5, tq = idx&31; 64 t each)
// ---------------------------------------------------------------------------
__global__ __launch_bounds__(256) void k_pack_all(
    const float* __restrict__ text, const float* __restrict__ W,
    const float* __restrict__ y, __hip_bfloat16* __restrict__ textS,
    __hip_bfloat16* __restrict__ textC, __hip_bfloat16* __restrict__ WP,
    __hip_bfloat16* __restrict__ yP) {
    __shared__ float tile[32][64];  // 8 KB (y branch only)
    const int blk = blockIdx.x;
    const int tid = threadIdx.x;

    if (blk < 32) {
        const int b = blk >> 3;
        const float* tb = text + (size_t)b * CT * SS;
        const int base = tid + (blk & 7) * 256;
        for (int e = base; e < 64 * 6 * 512; e += 2048) {
            int jj = e & 7, l = (e >> 3) & 63, cc = (e >> 9) % 6, st = e / 3072;
            int ct = cc * 32 + ((l >> 4) << 3) + jj;
            int s = st * 16 + (l & 15);
            textS[(size_t)b * 196608 + e] =
                __float2bfloat16(tb[(size_t)ct * SS + s]);
        }
        for (int e = base; e < 12 * 32 * 512; e += 2048) {
            int jj = e & 7, l = (e >> 3) & 63, scg = (e >> 9) & 31,
                ctt = e / 16384;
            int ct = ctt * 16 + (l & 15);
            int s = scg * 32 + ((l >> 4) << 3) + jj;
            textC[(size_t)b * 196608 + e] =
                __float2bfloat16(tb[(size_t)ct * SS + s]);
        }
    } else if (blk < 128) {
        const int k = (blk - 32) >> 3;
        const float* wk = W + (size_t)k * CC * CT;
        const int base = tid + ((blk - 32) & 7) * 256;
        for (int e = base; e < 12 * 24 * 512; e += 2048) {
            int j = e & 7, l = (e >> 3) & 63, oc = (e >> 9) % 24, nt = e / 12288;
            int ct = nt * 16 + (l & 15);
            int o = oc * 32 + ((l >> 4) << 3) + j;
            WP[(size_t)k * 147456 + e] =
                __float2bfloat16(wk[(size_t)o * CT + ct]);
        }
    } else {
        const int idx = blk - 128;
        const int b = idx >> 5;
        const int tq = idx & 31;
        const int t0 = tq * 64;
        const float* yb_ = y + (size_t)b * CC * TT;
        const int w = tid >> 6, l = tid & 63;
        const int l15 = l & 15, lg = l >> 4;
        const int row0 = tid >> 4;
        const int c4 = tid & 15;

        for (int oc = 0; oc < 24; ++oc) {
#pragma unroll
            for (int h = 0; h < 2; ++h) {
                const int row = row0 + h * 16;
                const float4 v = *reinterpret_cast<const float4*>(
                    yb_ + (size_t)(oc * 32 + row) * TT + t0 + c4 * 4);
                *reinterpret_cast<float4*>(&tile[row][c4 * 4]) = v;
            }
            __syncthreads();
            union {
                bfrag8 v8;
                short u[8];
            } A;
#pragma unroll
            for (int j = 0; j < 8; ++j)
                A.u[j] = (short)__bfloat16_as_ushort(
                    __float2bfloat16(tile[lg * 8 + j][w * 16 + l15]));
            __hip_bfloat16* dst =
                yP + (((size_t)(b * 128 + tq * 4 + w) * 24 + oc) * 512) +
                (size_t)l * 8;
            *reinterpret_cast<bfrag8*>(dst) = A.v8;
            __syncthreads();
        }
    }
}

// ---------------------------------------------------------------------------
// yW via MFMA (R10, proven). 1536 blocks, XCD b-affinity swizzle,
// wave = 3 nt x 4 ttg, epilogue via padded-LDS bounce -> b128 stores.
// ---------------------------------------------------------------------------
__global__ __launch_bounds__(256, 2) void k_yw_mfma(
    const __hip_bfloat16* __restrict__ yP, const __hip_bfloat16* __restrict__ WP,
    __hip_bfloat16* __restrict__ ywA) {
    const int i = blockIdx.x;
    const int x = i & 7, j = i >> 3;
    const int b = x & 3;
    const int k = j >> 4;
    const int tx = (j & 15) | ((x >> 2) << 4);
    const int kb = k * BB + b;

    const int tid = threadIdx.x;
    const int w = tid >> 6, l = tid & 63;
    const int l15 = l & 15, lg = l >> 4;
    const int ttg0 = tx * 4;
    const int nt0 = 3 * w;

    __shared__ float ot[4][16][197];  // 50.4 KB

    const short* ypb = reinterpret_cast<const short*>(yP) +
                       (((size_t)b * 128 + ttg0) * 24) * 512 + (size_t)l * 8;
    const short* wp = reinterpret_cast<const short*>(WP) +
                      (size_t)k * 147456 + (size_t)l * 8;

    f32x4 acc[3][4];
#pragma unroll
    for (int n = 0; n < 3; ++n)
#pragma unroll
        for (int tg = 0; tg < 4; ++tg) acc[n][tg] = (f32x4){0.f, 0.f, 0.f, 0.f};

    for (int oc = 0; oc < 24; ++oc) {
        bfrag8 af[4];
#pragma unroll
        for (int tg = 0; tg < 4; ++tg)
            af[tg] =
                *reinterpret_cast<const bfrag8*>(ypb + (tg * 24 + oc) * 512);
#pragma unroll
        for (int n = 0; n < 3; ++n) {
            bfrag8 bf = *reinterpret_cast<const bfrag8*>(
                wp + ((nt0 + n) * 24 + oc) * 512);
#pragma unroll
            for (int tg = 0; tg < 4; ++tg)
                acc[n][tg] = __builtin_amdgcn_mfma_f32_16x16x32_bf16(
                    af[tg], bf, acc[n][tg], 0, 0, 0);
        }
    }

#pragma unroll
    for (int n = 0; n < 3; ++n) {
        const int ct = (w * 3 + n) * 16 + l15;
#pragma unroll
        for (int tg = 0; tg < 4; ++tg)
#pragma unroll
            for (int r = 0; r < 4; ++r) ot[tg][lg * 4 + r][ct] = acc[n][tg][r];
    }
    __syncthreads();

    const size_t obase = ((size_t)kb * 128 + ttg0 + w) * 3072;
#pragma unroll
    for (int cc = 0; cc < 6; ++cc) {
        union {
            bfrag8 v8;
            short u[8];
        } A;
#pragma unroll
        for (int j2 = 0; j2 < 8; ++j2)
            A.u[j2] = (short)__bfloat16_as_ushort(
                __float2bfloat16(ot[w][l15][cc * 32 + lg * 8 + j2]));
        *reinterpret_cast<bfrag8*>(
            reinterpret_cast<short*>(ywA) + obase + cc * 512 + (size_t)l * 8) =
            A.v8;
    }
}

// ---------------------------------------------------------------------------
// yb[k,b,t] for all 12 k in one pass over y.
// ---------------------------------------------------------------------------
__global__ __launch_bounds__(256) void k_yb2(const float* __restrict__ y,
                                             const float* __restrict__ bias,
                                             float* __restrict__ yb) {
    const int b = blockIdx.y;
    const int t0 = blockIdx.x * 64;
    const int tid = threadIdx.x;
    const int tl = tid & 63, g = tid >> 6;

    __shared__ float bs[KK][CC];
    __shared__ float pb[4][64][KK];
    for (int i = tid; i < KK * CC; i += 256) bs[i / CC][i % CC] = bias[i];
    __syncthreads();

    float p[KK];
#pragma unroll
    for (int k = 0; k < KK; ++k) p[k] = 0.f;
    const float* yb_ = y + (size_t)b * CC * TT + t0 + tl;
    for (int o = g * 192; o < g * 192 + 192; ++o) {
        float v = yb_[(size_t)o * TT];
#pragma unroll
        for (int k = 0; k < KK; ++k) p[k] += v * bs[k][o];
    }
#pragma unroll
    for (int k = 0; k < KK; ++k) pb[g][tl][k] = p[k];
    __syncthreads();
    for (int i = tid; i < 64 * KK; i += 256) {
        int tt = i / KK, k = i % KK;
        float s = pb[0][tt][k] + pb[1][tt][k] + pb[2][tt][k] + pb[3][tt][k];
        yb[((size_t)k * BB + b) * TT + t0 + tt] = s;
    }
}

// ---------------------------------------------------------------------------
// FUSED attn (R9/R10 structure) + R11: software-pipelined textS loads.
// The st loop previously issued each bf load immediately before its MFMA;
// at 2 waves/SIMD the ~250-400cy L2 latency was fully exposed (counters:
// 334K cyc/wave vs ~20K of issue work). Now: MFMA on preloaded bfc[6] ->
// issue next st's 6 loads -> exp/pack VALU covers them.
// exp via exp2 with log2(e) folded into cfr (1 fewer VALU/element).
// ---------------------------------------------------------------------------
__global__ __launch_bounds__(512) void k_attn_fused(
    const float* __restrict__ ymask, const float* __restrict__ tmask,
    const float* __restrict__ scale, const __hip_bfloat16* __restrict__ ywA,
    const float* __restrict__ ybws, const __hip_bfloat16* __restrict__ textS,
    const __hip_bfloat16* __restrict__ textC, const float* __restrict__ y,
    const float* __restrict__ ge, float* __restrict__ out) {
    const int i = blockIdx.x;
    const int x = i & 7;
    const int b = x & 3;
    const int tt = (i >> 3) + ((x >> 2) << 6);
    const int t0 = tt * 16;
    const int tid = threadIdx.x;
    const int w = tid >> 6;       // 0..7
    const int l = tid & 63;
    const int l15 = l & 15, lg = l >> 4;
    const int ws0 = w * 128;

    __shared__ float lds_acc[8][8][64][4];   // 64 KB: prob-sum accumulator
    __shared__ uint2 exp_buf[2][8][8][64];   // 64 KB: [p][w][st][l] bf16 exp x4
    __shared__ float yb_s[KK][16];
    __shared__ float sc_s[KK];
    __shared__ __align__(16) float lred[2][2][16][8];  // [kp&1][p][row][w]

    if (tid < 192)
        yb_s[tid >> 4][tid & 15] =
            ybws[(size_t)((tid >> 4) * BB + b) * TT + t0 + (tid & 15)];
    if (tid < KK) sc_s[tid] = scale[tid];
    const f32x4 zero4 = (f32x4){0.f, 0.f, 0.f, 0.f};
#pragma unroll
    for (int st = 0; st < 8; ++st)
        *reinterpret_cast<f32x4*>(&lds_acc[w][st][l][0]) = zero4;
    __syncthreads();

    float tm2r[8];
#pragma unroll
    for (int st = 0; st < 8; ++st) {
        float m = tmask[b * SS + ws0 + st * 16 + l15];
        tm2r[st] = m * m;
    }
    float ymr[4];
#pragma unroll
    for (int r = 0; r < 4; ++r) ymr[r] = ymask[b * TT + t0 + lg * 4 + r];
    // 1/sqrt(768) * log2(e) folded together; exp(x) computed as exp2(x*log2e)
    const float invs_l2e = 0.03608439182435161f * 1.4426950408889634f;

    const short* ywAs = reinterpret_cast<const short*>(ywA);
    const short* tS = reinterpret_cast<const short*>(textS);
    const short* tSw = tS + (((size_t)b * 64 + w * 8) * 6) * 512 + (size_t)l * 8;
    const size_t headStride = (size_t)BB * 128 * 3072;  // shorts per head

    for (int kp = 0; kp < 6; ++kp) {
        // preload both heads' A-frags: 12 x 16B = 48 VGPR
        bfrag8 af[2][6];
        const size_t ab0 =
            (((size_t)(2 * kp * BB + b) * 128 + tt) * 6) * 512 + (size_t)l * 8;
#pragma unroll
        for (int cc = 0; cc < 6; ++cc) {
            af[0][cc] = *reinterpret_cast<const bfrag8*>(ywAs + ab0 + cc * 512);
            af[1][cc] = *reinterpret_cast<const bfrag8*>(ywAs + ab0 +
                                                         headStride + cc * 512);
        }
        float cfr[2][4], ybk[2][4];
#pragma unroll
        for (int p = 0; p < 2; ++p) {
            const int k = 2 * kp + p;
            const float sk = sc_s[k] * invs_l2e;
#pragma unroll
            for (int r = 0; r < 4; ++r) {
                const float cf = sk * ymr[r];
                cfr[p][r] = cf;
                ybk[p][r] = yb_s[k][lg * 4 + r] * cf;  // pre-scaled bias
            }
        }

        // prime the pipeline: st=0's B-frags
        bfrag8 bfc[6];
#pragma unroll
        for (int cc = 0; cc < 6; ++cc)
            bfc[cc] = *reinterpret_cast<const bfrag8*>(tSw + cc * 512);

        float lrow[2][4] = {{0.f, 0.f, 0.f, 0.f}, {0.f, 0.f, 0.f, 0.f}};
#pragma unroll
        for (int st = 0; st < 8; ++st) {
            f32x4 av0 = zero4, av1 = zero4;
            __builtin_amdgcn_s_setprio(1);
#pragma unroll
            for (int cc = 0; cc < 6; ++cc) {
                av0 = __builtin_amdgcn_mfma_f32_16x16x32_bf16(af[0][cc],
                                                              bfc[cc], av0, 0,
                                                              0, 0);
                av1 = __builtin_amdgcn_mfma_f32_16x16x32_bf16(af[1][cc],
                                                              bfc[cc], av1, 0,
                                                              0, 0);
            }
            __builtin_amdgcn_s_setprio(0);
            // issue next st's loads; latency hides under the exp VALU below
            if (st < 7) {
#pragma unroll
                for (int cc = 0; cc < 6; ++cc)
                    bfc[cc] = *reinterpret_cast<const bfrag8*>(
                        tSw + ((st + 1) * 6 + cc) * 512);
            }
            // scale+mask+exp2 (masked scores exp2(0)=1 participate, as ref)
#pragma unroll
            for (int r = 0; r < 4; ++r) {
                float e0 =
                    exp2f((av0[r] * cfr[0][r] + ybk[0][r]) * tm2r[st]);
                float e1 =
                    exp2f((av1[r] * cfr[1][r] + ybk[1][r]) * tm2r[st]);
                av0[r] = e0;
                av1[r] = e1;
                lrow[0][r] += e0;
                lrow[1][r] += e1;
            }
            exp_buf[0][w][st][l] =
                make_uint2(pk2(av0[0], av0[1]), pk2(av0[2], av0[3]));
            exp_buf[1][w][st][l] =
                make_uint2(pk2(av1[0], av1[1]), pk2(av1[2], av1[3]));
        }

        // block-wide denominator over S=1024
#pragma unroll
        for (int d = 1; d < 16; d <<= 1)
#pragma unroll
            for (int p = 0; p < 2; ++p)
#pragma unroll
                for (int r = 0; r < 4; ++r)
                    lrow[p][r] += __shfl_xor(lrow[p][r], d);
        if (l15 == 0) {
#pragma unroll
            for (int p = 0; p < 2; ++p)
#pragma unroll
                for (int r = 0; r < 4; ++r)
                    lred[kp & 1][p][lg * 4 + r][w] = lrow[p][r];
        }
        __syncthreads();
        float rl[2][4];
#pragma unroll
        for (int p = 0; p < 2; ++p)
#pragma unroll
            for (int r = 0; r < 4; ++r) {
                const float4 v0 = *reinterpret_cast<const float4*>(
                    &lred[kp & 1][p][lg * 4 + r][0]);
                const float4 v1 = *reinterpret_cast<const float4*>(
                    &lred[kp & 1][p][lg * 4 + r][4]);
                rl[p][r] = 1.0f / (v0.x + v0.y + v0.z + v0.w + v1.x + v1.y +
                                   v1.z + v1.w);
            }
        // read exp back, normalize, accumulate (all LDS, wave-private)
#pragma unroll
        for (int st = 0; st < 8; ++st) {
            const uint2 e0 = exp_buf[0][w][st][l];
            const uint2 e1 = exp_buf[1][w][st][l];
            f32x4 cur = *reinterpret_cast<f32x4*>(&lds_acc[w][st][l][0]);
            cur[0] += unpk_lo(e0.x) * rl[0][0] + unpk_lo(e1.x) * rl[1][0];
            cur[1] += unpk_hi(e0.x) * rl[0][1] + unpk_hi(e1.x) * rl[1][1];
            cur[2] += unpk_lo(e0.y) * rl[0][2] + unpk_lo(e1.y) * rl[1][2];
            cur[3] += unpk_hi(e0.y) * rl[0][3] + unpk_hi(e1.y) * rl[1][3];
            *reinterpret_cast<f32x4*>(&lds_acc[w][st][l][0]) = cur;
        }
        // lred[kp&1] safe to reuse at kp+2: reads above precede barrier(kp+1)
    }
    __builtin_amdgcn_s_waitcnt(0);  // own-wave lds_acc writes visible

    // ---------------- context phase ----------------
    const short* tC = reinterpret_cast<const short*>(textC);
    f32x4 cacc[12];
#pragma unroll
    for (int c = 0; c < 12; ++c) cacc[c] = (f32x4){0.f, 0.f, 0.f, 0.f};

#pragma unroll
    for (int sc = 0; sc < 4; ++sc) {
        const int scg = w * 4 + sc;
        union {
            bfrag8 v8;
            unsigned u[4];
        } A;
#pragma unroll
        for (int jp = 0; jp < 4; ++jp) {
            const int s0 = scg * 32 + lg * 8 + jp * 2;
            const int reg0 = s0 >> 7, st0 = (s0 >> 4) & 7;
            const int lo0 = (s0 & 15) | ((l15 >> 2) << 4);
            const int s1 = s0 + 1;
            const int lo1 = (s1 & 15) | ((l15 >> 2) << 4);
            const int ro = l15 & 3;
            float a = lds_acc[reg0][st0][lo0][ro];
            float bb2 = lds_acc[s1 >> 7][(s1 >> 4) & 7][lo1][ro];
            A.u[jp] = pk2(a, bb2);
        }
#pragma unroll
        for (int ctt = 0; ctt < 12; ++ctt) {
            bfrag8 bf = *reinterpret_cast<const bfrag8*>(
                tC + (((size_t)b * 12 + ctt) * 32 + scg) * 512 + (size_t)l * 8);
            cacc[ctt] = __builtin_amdgcn_mfma_f32_16x16x32_bf16(
                A.v8, bf, cacc[ctt], 0, 0, 0);
        }
    }
    __syncthreads();  // all lds_acc reads done before overwrite as 'part'

    float(*part)[16][192] =
        reinterpret_cast<float(*)[16][192]>(&lds_acc[0][0][0][0]);
    if (w < 4) {
#pragma unroll
        for (int ctt = 0; ctt < 12; ++ctt)
#pragma unroll
            for (int r = 0; r < 4; ++r)
                part[w][lg * 4 + r][ctt * 16 + l15] = cacc[ctt][r];
    }
    __syncthreads();
    if (w >= 4) {
#pragma unroll
        for (int ctt = 0; ctt < 12; ++ctt)
#pragma unroll
            for (int r = 0; r < 4; ++r)
                part[w - 4][lg * 4 + r][ctt * 16 + l15] += cacc[ctt][r];
    }
    __syncthreads();

    // epilogue: out[b,c,t0..t0+15] = y + ctx[t][c%192] + ge[b,c]
    const float* yb_ = y + (size_t)b * CC * TT;
    float* ob = out + (size_t)b * CC * TT;
    const float* geb = ge + b * CC;
    for (int c = tid; c < CC; c += 512) {
        const float gev = geb[c];
        const int cm = c % CT;
        const float4* ysrc =
            reinterpret_cast<const float4*>(yb_ + (size_t)c * TT + t0);
        float4* od = reinterpret_cast<float4*>(ob + (size_t)c * TT + t0);
#pragma unroll
        for (int i4 = 0; i4 < 4; ++i4) {
            float4 v = ysrc[i4];
            const int row = i4 * 4;
            v.x += part[0][row + 0][cm] + part[1][row + 0][cm] +
                   part[2][row + 0][cm] + part[3][row + 0][cm] + gev;
            v.y += part[0][row + 1][cm] + part[1][row + 1][cm] +
                   part[2][row + 1][cm] + part[3][row + 1][cm] + gev;
            v.z += part[0][row + 2][cm] + part[1][row + 2][cm] +
                   part[2][row + 2][cm] + part[3][row + 2][cm] + gev;
            v.w += part[0][row + 3][cm] + part[1][row + 3][cm] +
                   part[2][row + 3][cm] + part[3][row + 3][cm] + gev;
            od[i4] = v;
        }
    }
}

// ---------------------------------------------------------------------------
extern "C" void kernel_launch(void* const* d_in, const int* in_sizes, int n_in,
                              void* d_out, int out_size, void* d_ws,
                              size_t ws_size, hipStream_t stream) {
    const float* y      = (const float*)d_in[0];
    const float* ymask  = (const float*)d_in[1];
    const float* text   = (const float*)d_in[2];
    const float* tmask  = (const float*)d_in[3];
    const float* ge     = (const float*)d_in[4];
    const float* W      = (const float*)d_in[5];
    const float* bias   = (const float*)d_in[6];
    const float* scale  = (const float*)d_in[7];
    float* out = (float*)d_out;

    // workspace carve-up (bytes)
    char* ws = (char*)d_ws;
    __hip_bfloat16* ywA   = (__hip_bfloat16*)ws;                 // 37,748,736
    float*          ybws  = (float*)(ws + 37748736);             //    393,216
    __hip_bfloat16* textS = (__hip_bfloat16*)(ws + 38141952);    //  1,572,864
    __hip_bfloat16* textC = (__hip_bfloat16*)(ws + 39714816);    //  1,572,864
    __hip_bfloat16* yP    = (__hip_bfloat16*)(ws + 58064896);    // 12,582,912
    __hip_bfloat16* WP    = (__hip_bfloat16*)(ws + 70647808);    //  3,538,944

    k_pack_all<<<256, 256, 0, stream>>>(text, W, y, textS, textC, WP, yP);
    k_yb2<<<dim3(TT / 64, BB), 256, 0, stream>>>(y, bias, ybws);
    k_yw_mfma<<<1536, 256, 0, stream>>>(yP, WP, ywA);
    k_attn_fused<<<512, 512, 0, stream>>>(ymask, tmask, scale, ywA, ybws,
                                          textS, textC, y, ge, out);
}

// Round 12
// 221.057 us; speedup vs baseline: 1.1109x; 1.1109x over previous
//
#include <hip/hip_runtime.h>
#include <hip/hip_bf16.h>

// Problem constants
#define BB 4
#define CC 768
#define CT 192
#define TT 2048
#define SS 1024
#define KK 12

typedef __attribute__((ext_vector_type(8))) short bfrag8;  // 8 bf16 = 4 VGPR
typedef __attribute__((ext_vector_type(4))) float f32x4;

// ---------------------------------------------------------------------------
// Fragment-layout convention (16x16x32 bf16 MFMA):
//   A: row m = lane&15, k-slot = 32*cc + (lane>>4)*8 + j
//   B: col n = lane&15, k-slot = 32*cc + (lane>>4)*8 + j
//   D: col n = lane&15, row m = (lane>>4)*4 + reg   (HW-verified)
//
// HARD CONSTRAINTS (measured R7-R11):
//  - toolchain pins arch-VGPR budget at 128; live sets must stay ~<=120
//    (R11: +24 regs on R10's ~106 -> spill -> +25MB scratch, +17us).
//  - occupancy capped at 2 waves/SIMD (unified VGPR+AGPR) -> latency must
//    be hidden IN-wave.
// R12: af[2][6] (48 VGPR) was identical across all 8 waves -> moved to LDS
// (staged once per kp); freed registers fund the textS prefetch pipeline.
// ---------------------------------------------------------------------------

__device__ inline unsigned pk2(float a, float b) {
    __hip_bfloat162 h2;
    h2.x = __float2bfloat16(a);
    h2.y = __float2bfloat16(b);
    return *reinterpret_cast<unsigned*>(&h2);
}
__device__ inline float unpk_lo(unsigned u) { return __uint_as_float(u << 16); }
__device__ inline float unpk_hi(unsigned u) {
    return __uint_as_float(u & 0xffff0000u);
}

// ---------------------------------------------------------------------------
// ONE pack kernel, 256 blocks (R10, proven):
//   blk 0..31   : textS/textC  (b = blk>>3, part = blk&7)
//   blk 32..127 : WP           (k = (blk-32)>>3, part = (blk-32)&7)
//   blk 128..255: yP via LDS transpose (b = idx>>5, tq = idx&31; 64 t each)
// ---------------------------------------------------------------------------
__global__ __launch_bounds__(256) void k_pack_all(
    const float* __restrict__ text, const float* __restrict__ W,
    const float* __restrict__ y, __hip_bfloat16* __restrict__ textS,
    __hip_bfloat16* __restrict__ textC, __hip_bfloat16* __restrict__ WP,
    __hip_bfloat16* __restrict__ yP) {
    __shared__ float tile[32][64];  // 8 KB (y branch only)
    const int blk = blockIdx.x;
    const int tid = threadIdx.x;

    if (blk < 32) {
        const int b = blk >> 3;
        const float* tb = text + (size_t)b * CT * SS;
        const int base = tid + (blk & 7) * 256;
        for (int e = base; e < 64 * 6 * 512; e += 2048) {
            int jj = e & 7, l = (e >> 3) & 63, cc = (e >> 9) % 6, st = e / 3072;
            int ct = cc * 32 + ((l >> 4) << 3) + jj;
            int s = st * 16 + (l & 15);
            textS[(size_t)b * 196608 + e] =
                __float2bfloat16(tb[(size_t)ct * SS + s]);
        }
        for (int e = base; e < 12 * 32 * 512; e += 2048) {
            int jj = e & 7, l = (e >> 3) & 63, scg = (e >> 9) & 31,
                ctt = e / 16384;
            int ct = ctt * 16 + (l & 15);
            int s = scg * 32 + ((l >> 4) << 3) + jj;
            textC[(size_t)b * 196608 + e] =
                __float2bfloat16(tb[(size_t)ct * SS + s]);
        }
    } else if (blk < 128) {
        const int k = (blk - 32) >> 3;
        const float* wk = W + (size_t)k * CC * CT;
        const int base = tid + ((blk - 32) & 7) * 256;
        for (int e = base; e < 12 * 24 * 512; e += 2048) {
            int j = e & 7, l = (e >> 3) & 63, oc = (e >> 9) % 24, nt = e / 12288;
            int ct = nt * 16 + (l & 15);
            int o = oc * 32 + ((l >> 4) << 3) + j;
            WP[(size_t)k * 147456 + e] =
                __float2bfloat16(wk[(size_t)o * CT + ct]);
        }
    } else {
        const int idx = blk - 128;
        const int b = idx >> 5;
        const int tq = idx & 31;
        const int t0 = tq * 64;
        const float* yb_ = y + (size_t)b * CC * TT;
        const int w = tid >> 6, l = tid & 63;
        const int l15 = l & 15, lg = l >> 4;
        const int row0 = tid >> 4;
        const int c4 = tid & 15;

        for (int oc = 0; oc < 24; ++oc) {
#pragma unroll
            for (int h = 0; h < 2; ++h) {
                const int row = row0 + h * 16;
                const float4 v = *reinterpret_cast<const float4*>(
                    yb_ + (size_t)(oc * 32 + row) * TT + t0 + c4 * 4);
                *reinterpret_cast<float4*>(&tile[row][c4 * 4]) = v;
            }
            __syncthreads();
            union {
                bfrag8 v8;
                short u[8];
            } A;
#pragma unroll
            for (int j = 0; j < 8; ++j)
                A.u[j] = (short)__bfloat16_as_ushort(
                    __float2bfloat16(tile[lg * 8 + j][w * 16 + l15]));
            __hip_bfloat16* dst =
                yP + (((size_t)(b * 128 + tq * 4 + w) * 24 + oc) * 512) +
                (size_t)l * 8;
            *reinterpret_cast<bfrag8*>(dst) = A.v8;
            __syncthreads();
        }
    }
}

// ---------------------------------------------------------------------------
// yW via MFMA (R10, proven). 1536 blocks, XCD b-affinity swizzle,
// wave = 3 nt x 4 ttg, epilogue via padded-LDS bounce -> b128 stores.
// ---------------------------------------------------------------------------
__global__ __launch_bounds__(256, 2) void k_yw_mfma(
    const __hip_bfloat16* __restrict__ yP, const __hip_bfloat16* __restrict__ WP,
    __hip_bfloat16* __restrict__ ywA) {
    const int i = blockIdx.x;
    const int x = i & 7, j = i >> 3;
    const int b = x & 3;
    const int k = j >> 4;
    const int tx = (j & 15) | ((x >> 2) << 4);
    const int kb = k * BB + b;

    const int tid = threadIdx.x;
    const int w = tid >> 6, l = tid & 63;
    const int l15 = l & 15, lg = l >> 4;
    const int ttg0 = tx * 4;
    const int nt0 = 3 * w;

    __shared__ float ot[4][16][197];  // 50.4 KB

    const short* ypb = reinterpret_cast<const short*>(yP) +
                       (((size_t)b * 128 + ttg0) * 24) * 512 + (size_t)l * 8;
    const short* wp = reinterpret_cast<const short*>(WP) +
                      (size_t)k * 147456 + (size_t)l * 8;

    f32x4 acc[3][4];
#pragma unroll
    for (int n = 0; n < 3; ++n)
#pragma unroll
        for (int tg = 0; tg < 4; ++tg) acc[n][tg] = (f32x4){0.f, 0.f, 0.f, 0.f};

    for (int oc = 0; oc < 24; ++oc) {
        bfrag8 af[4];
#pragma unroll
        for (int tg = 0; tg < 4; ++tg)
            af[tg] =
                *reinterpret_cast<const bfrag8*>(ypb + (tg * 24 + oc) * 512);
#pragma unroll
        for (int n = 0; n < 3; ++n) {
            bfrag8 bf = *reinterpret_cast<const bfrag8*>(
                wp + ((nt0 + n) * 24 + oc) * 512);
#pragma unroll
            for (int tg = 0; tg < 4; ++tg)
                acc[n][tg] = __builtin_amdgcn_mfma_f32_16x16x32_bf16(
                    af[tg], bf, acc[n][tg], 0, 0, 0);
        }
    }

#pragma unroll
    for (int n = 0; n < 3; ++n) {
        const int ct = (w * 3 + n) * 16 + l15;
#pragma unroll
        for (int tg = 0; tg < 4; ++tg)
#pragma unroll
            for (int r = 0; r < 4; ++r) ot[tg][lg * 4 + r][ct] = acc[n][tg][r];
    }
    __syncthreads();

    const size_t obase = ((size_t)kb * 128 + ttg0 + w) * 3072;
#pragma unroll
    for (int cc = 0; cc < 6; ++cc) {
        union {
            bfrag8 v8;
            short u[8];
        } A;
#pragma unroll
        for (int j2 = 0; j2 < 8; ++j2)
            A.u[j2] = (short)__bfloat16_as_ushort(
                __float2bfloat16(ot[w][l15][cc * 32 + lg * 8 + j2]));
        *reinterpret_cast<bfrag8*>(
            reinterpret_cast<short*>(ywA) + obase + cc * 512 + (size_t)l * 8) =
            A.v8;
    }
}

// ---------------------------------------------------------------------------
// yb[k,b,t] for all 12 k in one pass over y.
// ---------------------------------------------------------------------------
__global__ __launch_bounds__(256) void k_yb2(const float* __restrict__ y,
                                             const float* __restrict__ bias,
                                             float* __restrict__ yb) {
    const int b = blockIdx.y;
    const int t0 = blockIdx.x * 64;
    const int tid = threadIdx.x;
    const int tl = tid & 63, g = tid >> 6;

    __shared__ float bs[KK][CC];
    __shared__ float pb[4][64][KK];
    for (int i = tid; i < KK * CC; i += 256) bs[i / CC][i % CC] = bias[i];
    __syncthreads();

    float p[KK];
#pragma unroll
    for (int k = 0; k < KK; ++k) p[k] = 0.f;
    const float* yb_ = y + (size_t)b * CC * TT + t0 + tl;
    for (int o = g * 192; o < g * 192 + 192; ++o) {
        float v = yb_[(size_t)o * TT];
#pragma unroll
        for (int k = 0; k < KK; ++k) p[k] += v * bs[k][o];
    }
#pragma unroll
    for (int k = 0; k < KK; ++k) pb[g][tl][k] = p[k];
    __syncthreads();
    for (int i = tid; i < 64 * KK; i += 256) {
        int tt = i / KK, k = i % KK;
        float s = pb[0][tt][k] + pb[1][tt][k] + pb[2][tt][k] + pb[3][tt][k];
        yb[((size_t)k * BB + b) * TT + t0 + tt] = s;
    }
}

// ---------------------------------------------------------------------------
// FUSED attn, R12:
//  - af (head-pair A-frags) staged in LDS once per kp: identical across all
//    8 waves (ab0 has no w term) -> kills 8x redundant L2 reads AND frees
//    48 VGPR that R11's spilled textS pipeline needed.
//  - textS prefetch pipeline (bfc) kept: MFMA on current frags -> issue next
//    st's 6 loads -> exp VALU covers the L2 latency.
//  - exp2 with log2(e) folded into cfr.
// LDS: lds_acc 64K + exp_buf 64K + af_s 24K + small = ~157.5 KB (<160).
// Live VGPRs ~95-105 (bfc rotation ~28 + av/lrow/masks + a0/a1 transients).
// ---------------------------------------------------------------------------
__global__ __launch_bounds__(512) void k_attn_fused(
    const float* __restrict__ ymask, const float* __restrict__ tmask,
    const float* __restrict__ scale, const __hip_bfloat16* __restrict__ ywA,
    const float* __restrict__ ybws, const __hip_bfloat16* __restrict__ textS,
    const __hip_bfloat16* __restrict__ textC, const float* __restrict__ y,
    const float* __restrict__ ge, float* __restrict__ out) {
    const int i = blockIdx.x;
    const int x = i & 7;
    const int b = x & 3;
    const int tt = (i >> 3) + ((x >> 2) << 6);
    const int t0 = tt * 16;
    const int tid = threadIdx.x;
    const int w = tid >> 6;       // 0..7
    const int l = tid & 63;
    const int l15 = l & 15, lg = l >> 4;
    const int ws0 = w * 128;

    __shared__ float lds_acc[8][8][64][4];          // 64 KB: prob-sum acc
    __shared__ uint2 exp_buf[2][8][8][64];          // 64 KB: bf16 exp x4
    __shared__ __align__(16) short af_s[2][6][64][8];  // 24 KB: shared A-frags
    __shared__ float yb_s[KK][16];
    __shared__ float sc_s[KK];
    __shared__ __align__(16) float lred[2][2][16][8];  // [kp&1][p][row][w]

    if (tid < 192)
        yb_s[tid >> 4][tid & 15] =
            ybws[(size_t)((tid >> 4) * BB + b) * TT + t0 + (tid & 15)];
    if (tid < KK) sc_s[tid] = scale[tid];
    const f32x4 zero4 = (f32x4){0.f, 0.f, 0.f, 0.f};
#pragma unroll
    for (int st = 0; st < 8; ++st)
        *reinterpret_cast<f32x4*>(&lds_acc[w][st][l][0]) = zero4;

    float tm2r[8];
#pragma unroll
    for (int st = 0; st < 8; ++st) {
        float m = tmask[b * SS + ws0 + st * 16 + l15];
        tm2r[st] = m * m;
    }
    float ymr[4];
#pragma unroll
    for (int r = 0; r < 4; ++r) ymr[r] = ymask[b * TT + t0 + lg * 4 + r];
    // 1/sqrt(768) * log2(e); exp(x) computed as exp2(x*log2e)
    const float invs_l2e = 0.03608439182435161f * 1.4426950408889634f;

    const short* ywAs = reinterpret_cast<const short*>(ywA);
    const short* tS = reinterpret_cast<const short*>(textS);
    const short* tSw = tS + (((size_t)b * 64 + w * 8) * 6) * 512 + (size_t)l * 8;
    const size_t headStride = (size_t)BB * 128 * 3072;  // shorts per head

    for (int kp = 0; kp < 6; ++kp) {
        // ---- stage the head-pair's A-frags into LDS (all waves share) ----
        // 768 bfrag8 units: p(2) x cc(6) x l2(64); 512 threads -> <=2 each.
        const size_t ab0_l0 =
            (((size_t)(2 * kp * BB + b) * 128 + tt) * 6) * 512;
        for (int u = tid; u < 768; u += 512) {
            const int p = u / 384;
            const int rem = u - p * 384;
            const int cc2 = rem >> 6;
            const int l2 = rem & 63;
            bfrag8 v = *reinterpret_cast<const bfrag8*>(
                ywAs + ab0_l0 + (size_t)p * headStride + cc2 * 512 + l2 * 8);
            *reinterpret_cast<bfrag8*>(&af_s[p][cc2][l2][0]) = v;
        }
        __syncthreads();  // af_s ready (also orders prev kp's lds_acc RMW)

        float cfr[2][4], ybk[2][4];
#pragma unroll
        for (int p = 0; p < 2; ++p) {
            const int k = 2 * kp + p;
            const float sk = sc_s[k] * invs_l2e;
#pragma unroll
            for (int r = 0; r < 4; ++r) {
                const float cf = sk * ymr[r];
                cfr[p][r] = cf;
                ybk[p][r] = yb_s[k][lg * 4 + r] * cf;  // pre-scaled bias
            }
        }

        // prime the textS pipeline: st=0's B-frags
        bfrag8 bfc[6];
#pragma unroll
        for (int cc = 0; cc < 6; ++cc)
            bfc[cc] = *reinterpret_cast<const bfrag8*>(tSw + cc * 512);

        float lrow[2][4] = {{0.f, 0.f, 0.f, 0.f}, {0.f, 0.f, 0.f, 0.f}};
#pragma unroll
        for (int st = 0; st < 8; ++st) {
            f32x4 av0 = zero4, av1 = zero4;
            __builtin_amdgcn_s_setprio(1);
#pragma unroll
            for (int cc = 0; cc < 6; ++cc) {
                bfrag8 a0 =
                    *reinterpret_cast<const bfrag8*>(&af_s[0][cc][l][0]);
                bfrag8 a1 =
                    *reinterpret_cast<const bfrag8*>(&af_s[1][cc][l][0]);
                av0 = __builtin_amdgcn_mfma_f32_16x16x32_bf16(a0, bfc[cc],
                                                              av0, 0, 0, 0);
                av1 = __builtin_amdgcn_mfma_f32_16x16x32_bf16(a1, bfc[cc],
                                                              av1, 0, 0, 0);
            }
            __builtin_amdgcn_s_setprio(0);
            // issue next st's textS loads; latency hides under exp VALU
            if (st < 7) {
#pragma unroll
                for (int cc = 0; cc < 6; ++cc)
                    bfc[cc] = *reinterpret_cast<const bfrag8*>(
                        tSw + ((st + 1) * 6 + cc) * 512);
            }
            // scale+mask+exp2 (masked scores exp2(0)=1 participate, as ref)
#pragma unroll
            for (int r = 0; r < 4; ++r) {
                float e0 = exp2f((av0[r] * cfr[0][r] + ybk[0][r]) * tm2r[st]);
                float e1 = exp2f((av1[r] * cfr[1][r] + ybk[1][r]) * tm2r[st]);
                av0[r] = e0;
                av1[r] = e1;
                lrow[0][r] += e0;
                lrow[1][r] += e1;
            }
            exp_buf[0][w][st][l] =
                make_uint2(pk2(av0[0], av0[1]), pk2(av0[2], av0[3]));
            exp_buf[1][w][st][l] =
                make_uint2(pk2(av1[0], av1[1]), pk2(av1[2], av1[3]));
        }

        // block-wide denominator over S=1024
#pragma unroll
        for (int d = 1; d < 16; d <<= 1)
#pragma unroll
            for (int p = 0; p < 2; ++p)
#pragma unroll
                for (int r = 0; r < 4; ++r)
                    lrow[p][r] += __shfl_xor(lrow[p][r], d);
        if (l15 == 0) {
#pragma unroll
            for (int p = 0; p < 2; ++p)
#pragma unroll
                for (int r = 0; r < 4; ++r)
                    lred[kp & 1][p][lg * 4 + r][w] = lrow[p][r];
        }
        __syncthreads();  // lred visible; all waves done reading af_s
        float rl[2][4];
#pragma unroll
        for (int p = 0; p < 2; ++p)
#pragma unroll
            for (int r = 0; r < 4; ++r) {
                const float4 v0 = *reinterpret_cast<const float4*>(
                    &lred[kp & 1][p][lg * 4 + r][0]);
                const float4 v1 = *reinterpret_cast<const float4*>(
                    &lred[kp & 1][p][lg * 4 + r][4]);
                rl[p][r] = 1.0f / (v0.x + v0.y + v0.z + v0.w + v1.x + v1.y +
                                   v1.z + v1.w);
            }
        // read exp back, normalize, accumulate (all LDS, wave-private)
#pragma unroll
        for (int st = 0; st < 8; ++st) {
            const uint2 e0 = exp_buf[0][w][st][l];
            const uint2 e1 = exp_buf[1][w][st][l];
            f32x4 cur = *reinterpret_cast<f32x4*>(&lds_acc[w][st][l][0]);
            cur[0] += unpk_lo(e0.x) * rl[0][0] + unpk_lo(e1.x) * rl[1][0];
            cur[1] += unpk_hi(e0.x) * rl[0][1] + unpk_hi(e1.x) * rl[1][1];
            cur[2] += unpk_lo(e0.y) * rl[0][2] + unpk_lo(e1.y) * rl[1][2];
            cur[3] += unpk_hi(e0.y) * rl[0][3] + unpk_hi(e1.y) * rl[1][3];
            *reinterpret_cast<f32x4*>(&lds_acc[w][st][l][0]) = cur;
        }
        // af_s overwrite at kp+1 is safe: this kp's 2nd barrier put every
        // wave past its st-loop (af_s reads); RMW above doesn't touch af_s.
    }
    __builtin_amdgcn_s_waitcnt(0);  // own-wave lds_acc writes visible

    // ---------------- context phase ----------------
    const short* tC = reinterpret_cast<const short*>(textC);
    f32x4 cacc[12];
#pragma unroll
    for (int c = 0; c < 12; ++c) cacc[c] = (f32x4){0.f, 0.f, 0.f, 0.f};

#pragma unroll
    for (int sc = 0; sc < 4; ++sc) {
        const int scg = w * 4 + sc;
        union {
            bfrag8 v8;
            unsigned u[4];
        } A;
#pragma unroll
        for (int jp = 0; jp < 4; ++jp) {
            const int s0 = scg * 32 + lg * 8 + jp * 2;
            const int reg0 = s0 >> 7, st0 = (s0 >> 4) & 7;
            const int lo0 = (s0 & 15) | ((l15 >> 2) << 4);
            const int s1 = s0 + 1;
            const int lo1 = (s1 & 15) | ((l15 >> 2) << 4);
            const int ro = l15 & 3;
            float a = lds_acc[reg0][st0][lo0][ro];
            float bb2 = lds_acc[s1 >> 7][(s1 >> 4) & 7][lo1][ro];
            A.u[jp] = pk2(a, bb2);
        }
#pragma unroll
        for (int ctt = 0; ctt < 12; ++ctt) {
            bfrag8 bf = *reinterpret_cast<const bfrag8*>(
                tC + (((size_t)b * 12 + ctt) * 32 + scg) * 512 + (size_t)l * 8);
            cacc[ctt] = __builtin_amdgcn_mfma_f32_16x16x32_bf16(
                A.v8, bf, cacc[ctt], 0, 0, 0);
        }
    }
    __syncthreads();  // all lds_acc reads done before overwrite as 'part'

    float(*part)[16][192] =
        reinterpret_cast<float(*)[16][192]>(&lds_acc[0][0][0][0]);
    if (w < 4) {
#pragma unroll
        for (int ctt = 0; ctt < 12; ++ctt)
#pragma unroll
            for (int r = 0; r < 4; ++r)
                part[w][lg * 4 + r][ctt * 16 + l15] = cacc[ctt][r];
    }
    __syncthreads();
    if (w >= 4) {
#pragma unroll
        for (int ctt = 0; ctt < 12; ++ctt)
#pragma unroll
            for (int r = 0; r < 4; ++r)
                part[w - 4][lg * 4 + r][ctt * 16 + l15] += cacc[ctt][r];
    }
    __syncthreads();

    // epilogue: out[b,c,t0..t0+15] = y + ctx[t][c%192] + ge[b,c]
    const float* yb_ = y + (size_t)b * CC * TT;
    float* ob = out + (size_t)b * CC * TT;
    const float* geb = ge + b * CC;
    for (int c = tid; c < CC; c += 512) {
        const float gev = geb[c];
        const int cm = c % CT;
        const float4* ysrc =
            reinterpret_cast<const float4*>(yb_ + (size_t)c * TT + t0);
        float4* od = reinterpret_cast<float4*>(ob + (size_t)c * TT + t0);
#pragma unroll
        for (int i4 = 0; i4 < 4; ++i4) {
            float4 v = ysrc[i4];
            const int row = i4 * 4;
            v.x += part[0][row + 0][cm] + part[1][row + 0][cm] +
                   part[2][row + 0][cm] + part[3][row + 0][cm] + gev;
            v.y += part[0][row + 1][cm] + part[1][row + 1][cm] +
                   part[2][row + 1][cm] + part[3][row + 1][cm] + gev;
            v.z += part[0][row + 2][cm] + part[1][row + 2][cm] +
                   part[2][row + 2][cm] + part[3][row + 2][cm] + gev;
            v.w += part[0][row + 3][cm] + part[1][row + 3][cm] +
                   part[2][row + 3][cm] + part[3][row + 3][cm] + gev;
            od[i4] = v;
        }
    }
}

// ---------------------------------------------------------------------------
extern "C" void kernel_launch(void* const* d_in, const int* in_sizes, int n_in,
                              void* d_out, int out_size, void* d_ws,
                              size_t ws_size, hipStream_t stream) {
    const float* y      = (const float*)d_in[0];
    const float* ymask  = (const float*)d_in[1];
    const float* text   = (const float*)d_in[2];
    const float* tmask  = (const float*)d_in[3];
    const float* ge     = (const float*)d_in[4];
    const float* W      = (const float*)d_in[5];
    const float* bias   = (const float*)d_in[6];
    const float* scale  = (const float*)d_in[7];
    float* out = (float*)d_out;

    // workspace carve-up (bytes)
    char* ws = (char*)d_ws;
    __hip_bfloat16* ywA   = (__hip_bfloat16*)ws;                 // 37,748,736
    float*          ybws  = (float*)(ws + 37748736);             //    393,216
    __hip_bfloat16* textS = (__hip_bfloat16*)(ws + 38141952);    //  1,572,864
    __hip_bfloat16* textC = (__hip_bfloat16*)(ws + 39714816);    //  1,572,864
    __hip_bfloat16* yP    = (__hip_bfloat16*)(ws + 58064896);    // 12,582,912
    __hip_bfloat16* WP    = (__hip_bfloat16*)(ws + 70647808);    //  3,538,944

    k_pack_all<<<256, 256, 0, stream>>>(text, W, y, textS, textC, WP, yP);
    k_yb2<<<dim3(TT / 64, BB), 256, 0, stream>>>(y, bias, ybws);
    k_yw_mfma<<<1536, 256, 0, stream>>>(yP, WP, ywA);
    k_attn_fused<<<512, 512, 0, stream>>>(ymask, tmask, scale, ywA, ybws,
                                          textS, textC, y, ge, out);
}